// Round 1
// baseline (730.319 us; speedup 1.0000x reference)
//
#include <hip/hip_runtime.h>
#include <stdint.h>

#define D_MODEL  1024
#define D_HIDDEN 4096
#define NE       8
#define T_TOK    8192
#define BM       128
#define BN       128
#define BK       64
#define MAXT     136
#define ROWS_CAP 17408

typedef __attribute__((ext_vector_type(8))) short short8;
typedef __attribute__((ext_vector_type(4))) float f32x4;

__device__ inline uint16_t f2bf(float f) {
  uint32_t u = __float_as_uint(f);
  uint32_t r = (u + 0x7fffu + ((u >> 16) & 1u)) >> 16;
  return (uint16_t)r;
}

#define GLOAD16(gp, lp) __builtin_amdgcn_global_load_lds( \
  (const __attribute__((address_space(1))) uint32_t*)(gp), \
  (__attribute__((address_space(3))) uint32_t*)(lp), 16, 0, 0)

// ---------------- transpose + f32->bf16 convert: in [R][C] -> out [C][R] ----
__global__ void transpose_cvt(const float* __restrict__ in, uint16_t* __restrict__ out,
                              int R, int C) {
  __shared__ float tile[32][33];
  size_t eoff = (size_t)blockIdx.z * R * C;
  in += eoff; out += eoff;
  int c0 = blockIdx.x * 32, r0 = blockIdx.y * 32;
  int x = threadIdx.x, y = threadIdx.y;
#pragma unroll
  for (int i = 0; i < 32; i += 8)
    tile[y + i][x] = in[(size_t)(r0 + y + i) * C + c0 + x];
  __syncthreads();
#pragma unroll
  for (int i = 0; i < 32; i += 8)
    out[(size_t)(c0 + y + i) * R + r0 + x] = f2bf(tile[x][y + i]);
}

// ---------------- router: logits, top-2, weights, expert bucketing ---------
__global__ void router_kernel(const float* __restrict__ x, const float* __restrict__ Wr,
                              const float* __restrict__ br,
                              int* __restrict__ cnt, int* __restrict__ tok_of,
                              int* __restrict__ k_of, float* __restrict__ tok_w) {
  int t = blockIdx.x * 4 + (threadIdx.x >> 6);
  int l = threadIdx.x & 63;
  const float* xr = x + (size_t)t * D_MODEL;
  float a[8] = {0.f,0.f,0.f,0.f,0.f,0.f,0.f,0.f};
  for (int d = l; d < D_MODEL; d += 64) {
    float xv = xr[d];
    const float4* w4 = (const float4*)(Wr + d * 8);
    float4 wa = w4[0], wb = w4[1];
    a[0] += xv * wa.x; a[1] += xv * wa.y; a[2] += xv * wa.z; a[3] += xv * wa.w;
    a[4] += xv * wb.x; a[5] += xv * wb.y; a[6] += xv * wb.z; a[7] += xv * wb.w;
  }
#pragma unroll
  for (int e = 0; e < 8; ++e) {
    float v = a[e];
#pragma unroll
    for (int off = 32; off > 0; off >>= 1) v += __shfl_xor(v, off);
    a[e] = v + br[e];
  }
  if (l == 0) {
    int i1 = 0; float v1 = a[0];
#pragma unroll
    for (int e = 1; e < 8; ++e) if (a[e] > v1) { v1 = a[e]; i1 = e; }
    int i2 = -1; float v2 = -1e30f;
#pragma unroll
    for (int e = 0; e < 8; ++e) if (e != i1 && a[e] > v2) { v2 = a[e]; i2 = e; }
    float e2 = __expf(v2 - v1);
    float inv = 1.0f / (1.0f + e2);
    int p1 = atomicAdd(cnt + i1, 1);
    tok_of[i1 * T_TOK + p1] = t; k_of[i1 * T_TOK + p1] = 0;
    int p2 = atomicAdd(cnt + i2, 1);
    tok_of[i2 * T_TOK + p2] = t; k_of[i2 * T_TOK + p2] = 1;
    tok_w[t * 2 + 0] = inv; tok_w[t * 2 + 1] = e2 * inv;
  }
}

// meta ints: [0]=ntiles, [1..9]=base[0..8] (padded prefix), [16..16+MAXT)=tile_e,
// [16+MAXT..16+2*MAXT)=tile_row0
__global__ void setup_kernel(const int* __restrict__ cnt, int* __restrict__ meta) {
  if (threadIdx.x != 0 || blockIdx.x != 0) return;
  int base = 0, nt = 0;
  meta[1] = 0;
  for (int e = 0; e < NE; ++e) {
    int c = cnt[e];
    int tiles = (c + BM - 1) / BM;
    for (int i = 0; i < tiles; ++i) {
      meta[16 + nt] = e;
      meta[16 + MAXT + nt] = base + i * BM;
      nt++;
    }
    base += tiles * BM;
    meta[2 + e] = base;
  }
  meta[0] = nt;
}

// ---------------- gather tokens into permuted bf16 buffer ------------------
__global__ void gather_kernel(const float* __restrict__ x, const int* __restrict__ cnt,
                              const int* __restrict__ meta, const int* __restrict__ tok_of,
                              const int* __restrict__ k_of,
                              uint16_t* __restrict__ xp, int* __restrict__ tok2row) {
  int r = blockIdx.x * 4 + (threadIdx.x >> 6);
  int l = threadIdx.x & 63;
  int total = meta[9];
  if (r >= total) return;
  int e = 0;
#pragma unroll
  for (int i = 1; i < 8; ++i) if (r >= meta[1 + i]) e = i;
  int p = r - meta[1 + e];
  uint16_t* dst = xp + (size_t)r * D_MODEL + l * 16;
  if (p < cnt[e]) {
    int t = tok_of[e * T_TOK + p];
    if (l == 0) tok2row[t * 2 + k_of[e * T_TOK + p]] = r;
    const float4* src = (const float4*)(x + (size_t)t * D_MODEL + l * 16);
    short8 o0, o1;
    float4 v0 = src[0], v1 = src[1], v2 = src[2], v3 = src[3];
    o0[0] = (short)f2bf(v0.x); o0[1] = (short)f2bf(v0.y);
    o0[2] = (short)f2bf(v0.z); o0[3] = (short)f2bf(v0.w);
    o0[4] = (short)f2bf(v1.x); o0[5] = (short)f2bf(v1.y);
    o0[6] = (short)f2bf(v1.z); o0[7] = (short)f2bf(v1.w);
    o1[0] = (short)f2bf(v2.x); o1[1] = (short)f2bf(v2.y);
    o1[2] = (short)f2bf(v2.z); o1[3] = (short)f2bf(v2.w);
    o1[4] = (short)f2bf(v3.x); o1[5] = (short)f2bf(v3.y);
    o1[6] = (short)f2bf(v3.z); o1[7] = (short)f2bf(v3.w);
    *(short8*)dst = o0;
    *(short8*)(dst + 8) = o1;
  } else {
    short8 z = {0,0,0,0,0,0,0,0};
    *(short8*)dst = z;
    *(short8*)(dst + 8) = z;
  }
}

// ---------------- grouped GEMM, 128x128 tile, BK=64, 16x16x32 bf16 MFMA ----
// A [rows][KD] bf16 (k-contig), Bt [NE][ND][KD] bf16 (k-contig rows = out cols)
template<int KD, int ND, bool RELU_BF16>
__global__ void moe_gemm(const uint16_t* __restrict__ A, const uint16_t* __restrict__ Bt,
                         const float* __restrict__ bias,
                         uint16_t* __restrict__ Cb, float* __restrict__ Cf,
                         const int* __restrict__ meta) {
  int nt = meta[0];
  int mt = blockIdx.y;
  if (mt >= nt) return;
  int e = meta[16 + mt];
  int row0 = meta[16 + MAXT + mt];
  int n0 = blockIdx.x * BN;

  __shared__ __align__(16) uint16_t lA[BM * BK];
  __shared__ __align__(16) uint16_t lB[BN * BK];

  int t = threadIdx.x;
  int w = t >> 6, l = t & 63;
  int wr = (w >> 1) * 64, wc = (w & 1) * 64;

  const uint16_t* Ab = A + (size_t)row0 * KD;
  const uint16_t* Bb = Bt + ((size_t)e * ND + n0) * KD;

  f32x4 acc[4][4];
#pragma unroll
  for (int m = 0; m < 4; ++m)
#pragma unroll
    for (int n = 0; n < 4; ++n) acc[m][n] = (f32x4){0.f, 0.f, 0.f, 0.f};

  int trow = t >> 3;          // 0..31
  int tcol = (t & 7) * 8;     // k element offset

  for (int kt = 0; kt < KD / BK; ++kt) {
    int k0 = kt * BK;
    __syncthreads();
#pragma unroll
    for (int i = 0; i < 4; ++i) {
      GLOAD16(Ab + (size_t)(i * 32 + trow) * KD + k0 + tcol, lA + (i * 32 + trow) * BK + tcol);
      GLOAD16(Bb + (size_t)(i * 32 + trow) * KD + k0 + tcol, lB + (i * 32 + trow) * BK + tcol);
    }
    asm volatile("s_waitcnt vmcnt(0)" ::: "memory");
    __syncthreads();
#pragma unroll
    for (int kk = 0; kk < 2; ++kk) {
      short8 af[4], bf[4];
      int ko = kk * 32 + (l >> 4) * 8;
#pragma unroll
      for (int m = 0; m < 4; ++m)
        af[m] = *(const short8*)(lA + (wr + m * 16 + (l & 15)) * BK + ko);
#pragma unroll
      for (int n = 0; n < 4; ++n)
        bf[n] = *(const short8*)(lB + (wc + n * 16 + (l & 15)) * BK + ko);
#pragma unroll
      for (int m = 0; m < 4; ++m)
#pragma unroll
        for (int n = 0; n < 4; ++n)
          acc[m][n] = __builtin_amdgcn_mfma_f32_16x16x32_bf16(af[m], bf[n], acc[m][n], 0, 0, 0);
    }
  }

#pragma unroll
  for (int m = 0; m < 4; ++m) {
    int row_b = row0 + wr + m * 16 + (l >> 4) * 4;
#pragma unroll
    for (int n = 0; n < 4; ++n) {
      int col = n0 + wc + n * 16 + (l & 15);
      float bv = bias[e * ND + col];
#pragma unroll
      for (int r = 0; r < 4; ++r) {
        float v = acc[m][n][r] + bv;
        size_t off = (size_t)(row_b + r) * ND + col;
        if (RELU_BF16) Cb[off] = f2bf(fmaxf(v, 0.f));
        else           Cf[off] = v;
      }
    }
  }
}

// ---------------- final combine: out[t] = w0*y[row0] + w1*y[row1] ----------
__global__ void combine_kernel(const float* __restrict__ y, const int* __restrict__ tok2row,
                               const float* __restrict__ tok_w, float* __restrict__ out) {
  int t = blockIdx.x;
  int i = threadIdx.x;
  int r0 = tok2row[t * 2], r1 = tok2row[t * 2 + 1];
  float w0 = tok_w[t * 2], w1 = tok_w[t * 2 + 1];
  float4 av = ((const float4*)(y + (size_t)r0 * D_MODEL))[i];
  float4 bv = ((const float4*)(y + (size_t)r1 * D_MODEL))[i];
  float4 res;
  res.x = w0 * av.x + w1 * bv.x;
  res.y = w0 * av.y + w1 * bv.y;
  res.z = w0 * av.z + w1 * bv.z;
  res.w = w0 * av.w + w1 * bv.w;
  ((float4*)(out + (size_t)t * D_MODEL))[i] = res;
}

extern "C" void kernel_launch(void* const* d_in, const int* in_sizes, int n_in,
                              void* d_out, int out_size, void* d_ws, size_t ws_size,
                              hipStream_t stream) {
  const float* x  = (const float*)d_in[0];
  const float* Wr = (const float*)d_in[1];
  const float* br = (const float*)d_in[2];
  const float* W1 = (const float*)d_in[3];
  const float* b1 = (const float*)d_in[4];
  const float* W2 = (const float*)d_in[5];
  const float* b2 = (const float*)d_in[6];
  float* out = (float*)d_out;

  char* ws = (char*)d_ws;
  size_t off = 0;
  auto alloc = [&](size_t bytes) -> void* {
    void* p = ws + off;
    off += (bytes + 255) & ~(size_t)255;
    return p;
  };
  uint16_t* W1T   = (uint16_t*)alloc((size_t)NE * D_MODEL * D_HIDDEN * 2);
  uint16_t* W2T   = (uint16_t*)alloc((size_t)NE * D_MODEL * D_HIDDEN * 2);
  uint16_t* xp    = (uint16_t*)alloc((size_t)ROWS_CAP * D_MODEL * 2);
  uint16_t* hp    = (uint16_t*)alloc((size_t)ROWS_CAP * D_HIDDEN * 2);
  float*    y     = (float*)alloc((size_t)ROWS_CAP * D_MODEL * 4);
  int*      cnt   = (int*)alloc(NE * 4);
  int*      tok_of= (int*)alloc((size_t)NE * T_TOK * 4);
  int*      k_of  = (int*)alloc((size_t)NE * T_TOK * 4);
  float*    tok_w = (float*)alloc(T_TOK * 2 * 4);
  int*      t2r   = (int*)alloc(T_TOK * 2 * 4);
  int*      meta  = (int*)alloc((16 + 2 * MAXT) * 4);

  if (ws_size < off) return;  // workspace too small: leave output untouched (visible failure)

  hipMemsetAsync(cnt, 0, NE * 4, stream);
  transpose_cvt<<<dim3(D_HIDDEN / 32, D_MODEL / 32, NE), dim3(32, 8), 0, stream>>>(
      W1, W1T, D_MODEL, D_HIDDEN);
  transpose_cvt<<<dim3(D_MODEL / 32, D_HIDDEN / 32, NE), dim3(32, 8), 0, stream>>>(
      W2, W2T, D_HIDDEN, D_MODEL);
  router_kernel<<<T_TOK / 4, 256, 0, stream>>>(x, Wr, br, cnt, tok_of, k_of, tok_w);
  setup_kernel<<<1, 64, 0, stream>>>(cnt, meta);
  gather_kernel<<<ROWS_CAP / 4, 256, 0, stream>>>(x, cnt, meta, tok_of, k_of, xp, t2r);
  moe_gemm<D_MODEL, D_HIDDEN, true><<<dim3(D_HIDDEN / BN, MAXT), 256, 0, stream>>>(
      xp, W1T, b1, hp, nullptr, meta);
  moe_gemm<D_HIDDEN, D_MODEL, false><<<dim3(D_MODEL / BN, MAXT), 256, 0, stream>>>(
      hp, W2T, b2, nullptr, y, meta);
  combine_kernel<<<T_TOK, 256, 0, stream>>>(y, t2r, tok_w, out);
}

// Round 2
// 677.787 us; speedup vs baseline: 1.0775x; 1.0775x over previous
//
#include <hip/hip_runtime.h>
#include <stdint.h>

#define D_MODEL  1024
#define D_HIDDEN 4096
#define NE       8
#define T_TOK    8192
#define BM       128
#define BN       128
#define BK       64
#define MAXT     136
#define ROWS_CAP 17408

typedef __attribute__((ext_vector_type(8))) short short8;
typedef __attribute__((ext_vector_type(4))) float f32x4;

__device__ inline uint16_t f2bf(float f) {
  uint32_t u = __float_as_uint(f);
  uint32_t r = (u + 0x7fffu + ((u >> 16) & 1u)) >> 16;
  return (uint16_t)r;
}

#define GLOAD16(gp, lp) __builtin_amdgcn_global_load_lds( \
  (const __attribute__((address_space(1))) uint32_t*)(gp), \
  (__attribute__((address_space(3))) uint32_t*)(lp), 16, 0, 0)

// ---------------- transpose + f32->bf16 convert: in [R][C] -> out [C][R] ----
__global__ void transpose_cvt(const float* __restrict__ in, uint16_t* __restrict__ out,
                              int R, int C) {
  __shared__ float tile[32][33];
  size_t eoff = (size_t)blockIdx.z * R * C;
  in += eoff; out += eoff;
  int c0 = blockIdx.x * 32, r0 = blockIdx.y * 32;
  int x = threadIdx.x, y = threadIdx.y;
#pragma unroll
  for (int i = 0; i < 32; i += 8)
    tile[y + i][x] = in[(size_t)(r0 + y + i) * C + c0 + x];
  __syncthreads();
#pragma unroll
  for (int i = 0; i < 32; i += 8)
    out[(size_t)(c0 + y + i) * R + r0 + x] = f2bf(tile[x][y + i]);
}

// ---------------- router: logits, top-2, weights, expert bucketing ---------
__global__ void router_kernel(const float* __restrict__ x, const float* __restrict__ Wr,
                              const float* __restrict__ br,
                              int* __restrict__ cnt, int* __restrict__ tok_of,
                              int* __restrict__ k_of, float* __restrict__ tok_w) {
  int t = blockIdx.x * 4 + (threadIdx.x >> 6);
  int l = threadIdx.x & 63;
  const float* xr = x + (size_t)t * D_MODEL;
  float a[8] = {0.f,0.f,0.f,0.f,0.f,0.f,0.f,0.f};
  for (int d = l; d < D_MODEL; d += 64) {
    float xv = xr[d];
    const float4* w4 = (const float4*)(Wr + d * 8);
    float4 wa = w4[0], wb = w4[1];
    a[0] += xv * wa.x; a[1] += xv * wa.y; a[2] += xv * wa.z; a[3] += xv * wa.w;
    a[4] += xv * wb.x; a[5] += xv * wb.y; a[6] += xv * wb.z; a[7] += xv * wb.w;
  }
#pragma unroll
  for (int e = 0; e < 8; ++e) {
    float v = a[e];
#pragma unroll
    for (int off = 32; off > 0; off >>= 1) v += __shfl_xor(v, off);
    a[e] = v + br[e];
  }
  if (l == 0) {
    int i1 = 0; float v1 = a[0];
#pragma unroll
    for (int e = 1; e < 8; ++e) if (a[e] > v1) { v1 = a[e]; i1 = e; }
    int i2 = -1; float v2 = -1e30f;
#pragma unroll
    for (int e = 0; e < 8; ++e) if (e != i1 && a[e] > v2) { v2 = a[e]; i2 = e; }
    float e2 = __expf(v2 - v1);
    float inv = 1.0f / (1.0f + e2);
    int p1 = atomicAdd(cnt + i1, 1);
    tok_of[i1 * T_TOK + p1] = t; k_of[i1 * T_TOK + p1] = 0;
    int p2 = atomicAdd(cnt + i2, 1);
    tok_of[i2 * T_TOK + p2] = t; k_of[i2 * T_TOK + p2] = 1;
    tok_w[t * 2 + 0] = inv; tok_w[t * 2 + 1] = e2 * inv;
  }
}

// meta ints: [0]=ntiles, [1..9]=base[0..8] (padded prefix), [16..16+MAXT)=tile_e,
// [16+MAXT..16+2*MAXT)=tile_row0
__global__ void setup_kernel(const int* __restrict__ cnt, int* __restrict__ meta) {
  if (threadIdx.x != 0 || blockIdx.x != 0) return;
  int base = 0, nt = 0;
  meta[1] = 0;
  for (int e = 0; e < NE; ++e) {
    int c = cnt[e];
    int tiles = (c + BM - 1) / BM;
    for (int i = 0; i < tiles; ++i) {
      meta[16 + nt] = e;
      meta[16 + MAXT + nt] = base + i * BM;
      nt++;
    }
    base += tiles * BM;
    meta[2 + e] = base;
  }
  meta[0] = nt;
}

// ---------------- gather tokens into permuted bf16 buffer ------------------
__global__ void gather_kernel(const float* __restrict__ x, const int* __restrict__ cnt,
                              const int* __restrict__ meta, const int* __restrict__ tok_of,
                              const int* __restrict__ k_of,
                              uint16_t* __restrict__ xp, int* __restrict__ tok2row) {
  int r = blockIdx.x * 4 + (threadIdx.x >> 6);
  int l = threadIdx.x & 63;
  int total = meta[9];
  if (r >= total) return;
  int e = 0;
#pragma unroll
  for (int i = 1; i < 8; ++i) if (r >= meta[1 + i]) e = i;
  int p = r - meta[1 + e];
  uint16_t* dst = xp + (size_t)r * D_MODEL + l * 16;
  if (p < cnt[e]) {
    int t = tok_of[e * T_TOK + p];
    if (l == 0) tok2row[t * 2 + k_of[e * T_TOK + p]] = r;
    const float4* src = (const float4*)(x + (size_t)t * D_MODEL + l * 16);
    short8 o0, o1;
    float4 v0 = src[0], v1 = src[1], v2 = src[2], v3 = src[3];
    o0[0] = (short)f2bf(v0.x); o0[1] = (short)f2bf(v0.y);
    o0[2] = (short)f2bf(v0.z); o0[3] = (short)f2bf(v0.w);
    o0[4] = (short)f2bf(v1.x); o0[5] = (short)f2bf(v1.y);
    o0[6] = (short)f2bf(v1.z); o0[7] = (short)f2bf(v1.w);
    o1[0] = (short)f2bf(v2.x); o1[1] = (short)f2bf(v2.y);
    o1[2] = (short)f2bf(v2.z); o1[3] = (short)f2bf(v2.w);
    o1[4] = (short)f2bf(v3.x); o1[5] = (short)f2bf(v3.y);
    o1[6] = (short)f2bf(v3.z); o1[7] = (short)f2bf(v3.w);
    *(short8*)dst = o0;
    *(short8*)(dst + 8) = o1;
  } else {
    short8 z = {0,0,0,0,0,0,0,0};
    *(short8*)dst = z;
    *(short8*)(dst + 8) = z;
  }
}

// ---------------- grouped GEMM, 128x128 tile, BK=64, 16x16x32 bf16 MFMA ----
// A [rows][KD] bf16 (k-contig), Bt [NE][ND][KD] bf16 (k-contig rows = out cols)
// LDS layout: linear dest for global_load_lds; data is stored XOR-swizzled by
// pre-swizzling the per-lane GLOBAL source column (rule #21): element col in
// LDS slot (col ^ ((row&7)<<3)). Reads apply the same XOR -> 2-way max.
template<int KD, int ND, bool RELU_BF16>
__global__ void moe_gemm(const uint16_t* __restrict__ A, const uint16_t* __restrict__ Bt,
                         const float* __restrict__ bias,
                         uint16_t* __restrict__ Cb, float* __restrict__ Cf,
                         const int* __restrict__ meta) {
  int nt = meta[0];
  int mt = blockIdx.y;
  if (mt >= nt) return;
  int e = meta[16 + mt];
  int row0 = meta[16 + MAXT + mt];
  int n0 = blockIdx.x * BN;

  __shared__ __align__(16) uint16_t lA[BM * BK];
  __shared__ __align__(16) uint16_t lB[BN * BK];

  int t = threadIdx.x;
  int w = t >> 6, l = t & 63;
  int wr = (w >> 1) * 64, wc = (w & 1) * 64;

  const uint16_t* Ab = A + (size_t)row0 * KD;
  const uint16_t* Bb = Bt + ((size_t)e * ND + n0) * KD;

  f32x4 acc[4][4];
#pragma unroll
  for (int m = 0; m < 4; ++m)
#pragma unroll
    for (int n = 0; n < 4; ++n) acc[m][n] = (f32x4){0.f, 0.f, 0.f, 0.f};

  int trow = t >> 3;                        // 0..31 (local row within 32-row chunk)
  int tcol = (t & 7) * 8;                   // linear LDS k-element offset
  int scol = tcol ^ ((trow & 7) << 3);      // swizzled global k-element offset

  for (int kt = 0; kt < KD / BK; ++kt) {
    int k0 = kt * BK;
    __syncthreads();
#pragma unroll
    for (int i = 0; i < 4; ++i) {
      GLOAD16(Ab + (size_t)(i * 32 + trow) * KD + k0 + scol, lA + (i * 32 + trow) * BK + tcol);
      GLOAD16(Bb + (size_t)(i * 32 + trow) * KD + k0 + scol, lB + (i * 32 + trow) * BK + tcol);
    }
    asm volatile("s_waitcnt vmcnt(0)" ::: "memory");
    __syncthreads();
#pragma unroll
    for (int kk = 0; kk < 2; ++kk) {
      short8 af[4], bf[4];
      int ko = kk * 32 + (l >> 4) * 8;
      int sw = ((l & 7) << 3);              // (row&7)<<3 for row = base + (l&15)
#pragma unroll
      for (int m = 0; m < 4; ++m)
        af[m] = *(const short8*)(lA + (wr + m * 16 + (l & 15)) * BK + (ko ^ sw));
#pragma unroll
      for (int n = 0; n < 4; ++n)
        bf[n] = *(const short8*)(lB + (wc + n * 16 + (l & 15)) * BK + (ko ^ sw));
#pragma unroll
      for (int m = 0; m < 4; ++m)
#pragma unroll
        for (int n = 0; n < 4; ++n)
          acc[m][n] = __builtin_amdgcn_mfma_f32_16x16x32_bf16(af[m], bf[n], acc[m][n], 0, 0, 0);
    }
  }

#pragma unroll
  for (int m = 0; m < 4; ++m) {
    int row_b = row0 + wr + m * 16 + (l >> 4) * 4;
#pragma unroll
    for (int n = 0; n < 4; ++n) {
      int col = n0 + wc + n * 16 + (l & 15);
      float bv = bias[e * ND + col];
#pragma unroll
      for (int r = 0; r < 4; ++r) {
        float v = acc[m][n][r] + bv;
        size_t off = (size_t)(row_b + r) * ND + col;
        if (RELU_BF16) Cb[off] = f2bf(fmaxf(v, 0.f));
        else           Cf[off] = v;
      }
    }
  }
}

// ---------------- final combine: out[t] = w0*y[row0] + w1*y[row1] ----------
__global__ void combine_kernel(const float* __restrict__ y, const int* __restrict__ tok2row,
                               const float* __restrict__ tok_w, float* __restrict__ out) {
  int t = blockIdx.x;
  int i = threadIdx.x;
  int r0 = tok2row[t * 2], r1 = tok2row[t * 2 + 1];
  float w0 = tok_w[t * 2], w1 = tok_w[t * 2 + 1];
  float4 av = ((const float4*)(y + (size_t)r0 * D_MODEL))[i];
  float4 bv = ((const float4*)(y + (size_t)r1 * D_MODEL))[i];
  float4 res;
  res.x = w0 * av.x + w1 * bv.x;
  res.y = w0 * av.y + w1 * bv.y;
  res.z = w0 * av.z + w1 * bv.z;
  res.w = w0 * av.w + w1 * bv.w;
  ((float4*)(out + (size_t)t * D_MODEL))[i] = res;
}

extern "C" void kernel_launch(void* const* d_in, const int* in_sizes, int n_in,
                              void* d_out, int out_size, void* d_ws, size_t ws_size,
                              hipStream_t stream) {
  const float* x  = (const float*)d_in[0];
  const float* Wr = (const float*)d_in[1];
  const float* br = (const float*)d_in[2];
  const float* W1 = (const float*)d_in[3];
  const float* b1 = (const float*)d_in[4];
  const float* W2 = (const float*)d_in[5];
  const float* b2 = (const float*)d_in[6];
  float* out = (float*)d_out;

  char* ws = (char*)d_ws;
  size_t off = 0;
  auto alloc = [&](size_t bytes) -> void* {
    void* p = ws + off;
    off += (bytes + 255) & ~(size_t)255;
    return p;
  };
  uint16_t* W1T   = (uint16_t*)alloc((size_t)NE * D_MODEL * D_HIDDEN * 2);
  uint16_t* W2T   = (uint16_t*)alloc((size_t)NE * D_MODEL * D_HIDDEN * 2);
  uint16_t* xp    = (uint16_t*)alloc((size_t)ROWS_CAP * D_MODEL * 2);
  uint16_t* hp    = (uint16_t*)alloc((size_t)ROWS_CAP * D_HIDDEN * 2);
  float*    y     = (float*)alloc((size_t)ROWS_CAP * D_MODEL * 4);
  int*      cnt   = (int*)alloc(NE * 4);
  int*      tok_of= (int*)alloc((size_t)NE * T_TOK * 4);
  int*      k_of  = (int*)alloc((size_t)NE * T_TOK * 4);
  float*    tok_w = (float*)alloc(T_TOK * 2 * 4);
  int*      t2r   = (int*)alloc(T_TOK * 2 * 4);
  int*      meta  = (int*)alloc((16 + 2 * MAXT) * 4);

  if (ws_size < off) return;  // workspace too small: leave output untouched (visible failure)

  hipMemsetAsync(cnt, 0, NE * 4, stream);
  transpose_cvt<<<dim3(D_HIDDEN / 32, D_MODEL / 32, NE), dim3(32, 8), 0, stream>>>(
      W1, W1T, D_MODEL, D_HIDDEN);
  transpose_cvt<<<dim3(D_MODEL / 32, D_HIDDEN / 32, NE), dim3(32, 8), 0, stream>>>(
      W2, W2T, D_HIDDEN, D_MODEL);
  router_kernel<<<T_TOK / 4, 256, 0, stream>>>(x, Wr, br, cnt, tok_of, k_of, tok_w);
  setup_kernel<<<1, 64, 0, stream>>>(cnt, meta);
  gather_kernel<<<ROWS_CAP / 4, 256, 0, stream>>>(x, cnt, meta, tok_of, k_of, xp, t2r);
  moe_gemm<D_MODEL, D_HIDDEN, true><<<dim3(D_HIDDEN / BN, MAXT), 256, 0, stream>>>(
      xp, W1T, b1, hp, nullptr, meta);
  moe_gemm<D_HIDDEN, D_MODEL, false><<<dim3(D_MODEL / BN, MAXT), 256, 0, stream>>>(
      hp, W2T, b2, nullptr, y, meta);
  combine_kernel<<<T_TOK, 256, 0, stream>>>(y, t2r, tok_w, out);
}